// Round 1
// baseline (7013.892 us; speedup 1.0000x reference)
//
#include <hip/hip_runtime.h>
#include <hip/hip_bf16.h>
#include <math.h>

#define D_IN 56
#define H    501
#define T_STEPS 277
#define O_OUT 76
#define BATCH 256
#define HP   512    // padded K (hidden) for MFMA
#define NP   1504   // padded 3H

typedef __attribute__((ext_vector_type(8))) short s16x8;
typedef __attribute__((ext_vector_type(4))) float f32x4;

__device__ __forceinline__ short f2bf(float x) {
    union { float f; unsigned u; } v; v.f = x;
    unsigned r = (v.u + 0x7fffu + ((v.u >> 16) & 1u)) >> 16;
    return (short)r;
}
__device__ __forceinline__ float bf2f(short b) {
    union { unsigned u; float f; } v; v.u = ((unsigned)(unsigned short)b) << 16;
    return v.f;
}

// ---------------------------------------------------------------------------
// Pack GRU weights into MFMA B-fragment order, gate-sliced per unit-block:
// dst tile index = (j*3 + g)*KT + ktp ; within tile: [lane][8 halves]
// slice j owns hidden units [16j, 16j+16); gate g row = g*H + u.
// KT==32: ktp 0..15 from w_ih, 16..31 from w_hh.  KT==16: w_hh only.
// ---------------------------------------------------------------------------
__global__ void k_pack_gru(const float* __restrict__ w_ih,
                           const float* __restrict__ w_hh,
                           short* __restrict__ dst, int KT) {
    int tile = blockIdx.x;
    int ktp  = tile % KT;
    int g    = (tile / KT) % 3;
    int j    = tile / (KT * 3);
    int l    = threadIdx.x;          // 0..63
    int u    = j * 16 + (l & 15);
    int row  = g * H + u;
    const float* src; int k0;
    if (KT == 32) {
        if (ktp < 16) { src = w_ih; k0 = ktp * 32; }
        else          { src = w_hh; k0 = (ktp - 16) * 32; }
    } else          { src = w_hh; k0 = ktp * 32; }
    k0 += (l >> 4) * 8;
    short* p = dst + ((size_t)tile * 64 + l) * 8;
    for (int jj = 0; jj < 8; jj++) {
        int k = k0 + jj;
        float v = 0.f;
        if (u < H && k < H) v = src[(size_t)row * H + k];
        p[jj] = f2bf(v);
    }
}

__global__ void k_pack_fc2(const float* __restrict__ w, short* __restrict__ dst) {
    int tile = blockIdx.x;           // mt*16 + kt, mt<5, kt<16
    int kt = tile % 16, mt = tile / 16;
    int l = threadIdx.x;
    int o = mt * 16 + (l & 15);
    int k0 = kt * 32 + (l >> 4) * 8;
    short* p = dst + ((size_t)tile * 64 + l) * 8;
    for (int jj = 0; jj < 8; jj++) {
        int k = k0 + jj; float v = 0.f;
        if (o < O_OUT && k < H) v = w[(size_t)o * H + k];
        p[jj] = f2bf(v);
    }
}

// ---------------------------------------------------------------------------
// fc1 + relu:  hin[b][0..63] (padded)
// ---------------------------------------------------------------------------
__global__ void k_hin(const float* __restrict__ x, const float* __restrict__ w,
                      const float* __restrict__ bias, float* __restrict__ hin) {
    int b = blockIdx.x, o = threadIdx.x;
    float acc = 0.f;
    if (o < D_IN) {
        acc = bias[o];
        for (int k = 0; k < D_IN; k++) acc += x[b * D_IN + k] * w[o * D_IN + k];
        acc = fmaxf(acc, 0.f);
    }
    hin[b * 64 + o] = (o < D_IN) ? acc : 0.f;
}

// g0[b][NP] = hin[b] @ w_ih0^T + b_ih0   (constant over t; fp32)
__global__ void k_g0(const float* __restrict__ hin, const float* __restrict__ w_ih0,
                     const float* __restrict__ b_ih0, float* __restrict__ g0) {
    int b = blockIdx.x, tid = threadIdx.x;
    __shared__ float sh[D_IN];
    if (tid < D_IN) sh[tid] = hin[b * 64 + tid];
    __syncthreads();
    for (int o = tid; o < NP; o += 256) {
        float acc = 0.f;
        if (o < 3 * H) {
            acc = b_ih0[o];
            for (int k = 0; k < D_IN; k++) acc += sh[k] * w_ih0[(size_t)o * D_IN + k];
        }
        g0[(size_t)b * NP + o] = acc;
    }
}

// ---------------------------------------------------------------------------
// One GRU timestep. grid = (32 unit-slices, 8 batch-groups of 32 rows).
// HAS_X: 6 waves, wave = (nt<<1)|part; part0 accumulates x@Wih (ktp 0..15),
// part1 accumulates h@Whh (ktp 16..31). !HAS_X: 3 waves, h-part only (layer0;
// input gates come precomputed in g0).
// h double-buffered globally (h_in read, h_out written) to avoid the
// cross-block write race within one launch.
// ---------------------------------------------------------------------------
template <bool HAS_X>
__global__ __launch_bounds__(HAS_X ? 384 : 192, 1)
void k_gru_step(const short* __restrict__ wpack,
                const short* __restrict__ ys_prev,   // null if !HAS_X
                const short* __restrict__ h_in,
                short* __restrict__ h_out,
                const float* __restrict__ g0,        // used if !HAS_X
                const float* __restrict__ b_ih,      // used if HAS_X
                const float* __restrict__ b_hh,
                short* __restrict__ ys_out,
                int t) {
    const int j    = blockIdx.x;          // unit slice 0..31
    const int b0   = blockIdx.y * 32;     // batch group base
    const int tid  = threadIdx.x;
    const int lane = tid & 63;
    const int wave = tid >> 6;
    const int NT   = HAS_X ? 384 : 192;
    const int KT   = HAS_X ? 32 : 16;

    __shared__ __align__(16) short sh[32 * 520];     // h slice, bf16, padded stride
    __shared__ float hg[6][32 * 17];                 // [gate*2+part][m][u]

    // stage h rows b0..b0+31 (full K) into LDS
    for (int c = tid; c < 2048; c += NT) {
        int row = c >> 6, cc = c & 63;
        *(s16x8*)&sh[row * 520 + cc * 8] =
            *(const s16x8*)&h_in[(size_t)(b0 + row) * HP + cc * 8];
    }
    __syncthreads();

    int nt, part;
    if (HAS_X) { nt = wave >> 1; part = wave & 1; }
    else       { nt = wave;      part = 1;        }

    const short* ws = wpack + (size_t)(j * 3 + nt) * KT * 64 * 8;
    const int arow = lane & 15;
    const int acol = (lane >> 4) * 8;

    f32x4 acc0 = {0.f, 0.f, 0.f, 0.f};
    f32x4 acc1 = {0.f, 0.f, 0.f, 0.f};
    for (int kk = 0; kk < 16; kk++) {
        int ktp = part ? (HAS_X ? kk + 16 : kk) : kk;
        s16x8 bfrag = *(const s16x8*)&ws[((size_t)ktp * 64 + lane) * 8];
        s16x8 a0, a1;
        if (HAS_X && part == 0) {
            // x operand straight from global (ys_prev[t])
            a0 = *(const s16x8*)&ys_prev[((size_t)t * BATCH + b0 + arow) * HP + kk * 32 + acol];
            a1 = *(const s16x8*)&ys_prev[((size_t)t * BATCH + b0 + 16 + arow) * HP + kk * 32 + acol];
        } else {
            a0 = *(const s16x8*)&sh[arow * 520 + kk * 32 + acol];
            a1 = *(const s16x8*)&sh[(16 + arow) * 520 + kk * 32 + acol];
        }
        acc0 = __builtin_amdgcn_mfma_f32_16x16x32_bf16(a0, bfrag, acc0, 0, 0, 0);
        acc1 = __builtin_amdgcn_mfma_f32_16x16x32_bf16(a1, bfrag, acc1, 0, 0, 0);
    }
    {   // C layout: m = (lane>>4)*4 + r, u = lane&15
        float* dsta = hg[nt * 2 + part];
        int u_l = lane & 15, mrow = (lane >> 4) * 4;
        for (int r = 0; r < 4; r++) {
            dsta[(mrow + r) * 17 + u_l]      = acc0[r];
            dsta[(16 + mrow + r) * 17 + u_l] = acc1[r];
        }
    }
    __syncthreads();

    // gate math + state update
    for (int idx = tid; idx < 512; idx += NT) {
        int m = idx >> 4, u_l = idx & 15;
        int b = b0 + m, u = j * 16 + u_l;
        size_t ysoff = ((size_t)t * BATCH + b) * HP + u;
        size_t hoff  = (size_t)b * HP + u;
        if (u >= H) { ys_out[ysoff] = 0; h_out[hoff] = 0; continue; }
        float hr = hg[1][m * 17 + u_l];
        float hz = hg[3][m * 17 + u_l];
        float hn = hg[5][m * 17 + u_l];
        float xr, xz, xn;
        if (HAS_X) {
            xr = hg[0][m * 17 + u_l] + b_ih[u];
            xz = hg[2][m * 17 + u_l] + b_ih[H + u];
            xn = hg[4][m * 17 + u_l] + b_ih[2 * H + u];
        } else {
            xr = g0[(size_t)b * NP + u];
            xz = g0[(size_t)b * NP + H + u];
            xn = g0[(size_t)b * NP + 2 * H + u];
        }
        float rg = 1.f / (1.f + __expf(-(xr + hr + b_hh[u])));
        float zg = 1.f / (1.f + __expf(-(xz + hz + b_hh[H + u])));
        float ng = tanhf(xn + rg * (hn + b_hh[2 * H + u]));
        float hold = bf2f(sh[m * 520 + u]);
        float hnew = (1.f - zg) * ng + zg * hold;
        short hb = f2bf(hnew);
        h_out[hoff]   = hb;
        ys_out[ysoff] = hb;
    }
}

// ---------------------------------------------------------------------------
// fc2 + transpose: out[b][o][t] = ys2[t][b][:] . fc2_w[o][:] + fc2_b[o]
// one block per batch element; MFMA with A = fc2_w (packed), B = ys2 rows (t)
// ---------------------------------------------------------------------------
__global__ __launch_bounds__(256, 1)
void k_fc2(const short* __restrict__ ys2, const short* __restrict__ fc2p,
           const float* __restrict__ fc2_b, float* __restrict__ out) {
    int b = blockIdx.x;
    int tid = threadIdx.x, lane = tid & 63, wave = tid >> 6;
    const s16x8 zf = {0, 0, 0, 0, 0, 0, 0, 0};
    for (int ntile = wave; ntile < 18; ntile += 4) {
        int tt = ntile * 16 + (lane & 15);
        s16x8 bf[16];
        for (int kt = 0; kt < 16; kt++) {
            if (tt < T_STEPS)
                bf[kt] = *(const s16x8*)&ys2[((size_t)tt * BATCH + b) * HP + kt * 32 + (lane >> 4) * 8];
            else
                bf[kt] = zf;
        }
        for (int mt = 0; mt < 5; mt++) {
            f32x4 acc = {0.f, 0.f, 0.f, 0.f};
            for (int kt = 0; kt < 16; kt++) {
                s16x8 af = *(const s16x8*)&fc2p[(((size_t)mt * 16 + kt) * 64 + lane) * 8];
                acc = __builtin_amdgcn_mfma_f32_16x16x32_bf16(af, bf[kt], acc, 0, 0, 0);
            }
            int obase = mt * 16 + (lane >> 4) * 4;
            for (int r = 0; r < 4; r++) {
                int o = obase + r;
                if (o < O_OUT && tt < T_STEPS)
                    out[((size_t)b * O_OUT + o) * T_STEPS + tt] = acc[r] + fc2_b[o];
            }
        }
    }
}

// ---------------------------------------------------------------------------
extern "C" void kernel_launch(void* const* d_in, const int* in_sizes, int n_in,
                              void* d_out, int out_size, void* d_ws, size_t ws_size,
                              hipStream_t stream) {
    const float* x     = (const float*)d_in[0];
    const float* fc1_w = (const float*)d_in[1];
    const float* fc1_b = (const float*)d_in[2];
    const float* w_ih0 = (const float*)d_in[3];
    const float* w_hh0 = (const float*)d_in[4];
    const float* b_ih0 = (const float*)d_in[5];
    const float* b_hh0 = (const float*)d_in[6];
    const float* w_ih1 = (const float*)d_in[7];
    const float* w_hh1 = (const float*)d_in[8];
    const float* b_ih1 = (const float*)d_in[9];
    const float* b_hh1 = (const float*)d_in[10];
    const float* w_ih2 = (const float*)d_in[11];
    const float* w_hh2 = (const float*)d_in[12];
    const float* b_ih2 = (const float*)d_in[13];
    const float* b_hh2 = (const float*)d_in[14];
    const float* fc2_w = (const float*)d_in[15];
    const float* fc2_b = (const float*)d_in[16];
    float* out = (float*)d_out;

    char* p = (char*)d_ws;
    auto alloc = [&](size_t bytes) {
        char* r = p; p += (bytes + 255) & ~(size_t)255; return r;
    };
    short* packW0 = (short*)alloc((size_t)32 * 3 * 16 * 64 * 8 * 2);
    short* packW1 = (short*)alloc((size_t)32 * 3 * 32 * 64 * 8 * 2);
    short* packW2 = (short*)alloc((size_t)32 * 3 * 32 * 64 * 8 * 2);
    short* packF  = (short*)alloc((size_t)80 * 64 * 8 * 2);
    float* hin    = (float*)alloc((size_t)BATCH * 64 * 4);
    float* g0     = (float*)alloc((size_t)BATCH * NP * 4);
    short* hsa    = (short*)alloc((size_t)BATCH * HP * 2);
    short* hsb    = (short*)alloc((size_t)BATCH * HP * 2);
    short* ysA    = (short*)alloc((size_t)T_STEPS * BATCH * HP * 2);
    short* ysB    = (short*)alloc((size_t)T_STEPS * BATCH * HP * 2);

    k_pack_gru<<<32 * 3 * 16, 64, 0, stream>>>(nullptr, w_hh0, packW0, 16);
    k_pack_gru<<<32 * 3 * 32, 64, 0, stream>>>(w_ih1, w_hh1, packW1, 32);
    k_pack_gru<<<32 * 3 * 32, 64, 0, stream>>>(w_ih2, w_hh2, packW2, 32);
    k_pack_fc2<<<80, 64, 0, stream>>>(fc2_w, packF);
    k_hin<<<BATCH, 64, 0, stream>>>(x, fc1_w, fc1_b, hin);
    k_g0<<<BATCH, 256, 0, stream>>>(hin, w_ih0, b_ih0, g0);

    dim3 grid(32, 8);
    // layer 0 (input gates constant = g0)
    hipMemsetAsync(hsa, 0, (size_t)BATCH * HP * 2, stream);
    for (int t = 0; t < T_STEPS; t++) {
        short* hr = (t & 1) ? hsb : hsa;
        short* hw = (t & 1) ? hsa : hsb;
        k_gru_step<false><<<grid, 192, 0, stream>>>(packW0, nullptr, hr, hw,
                                                    g0, nullptr, b_hh0, ysA, t);
    }
    // layer 1
    hipMemsetAsync(hsa, 0, (size_t)BATCH * HP * 2, stream);
    for (int t = 0; t < T_STEPS; t++) {
        short* hr = (t & 1) ? hsb : hsa;
        short* hw = (t & 1) ? hsa : hsb;
        k_gru_step<true><<<grid, 384, 0, stream>>>(packW1, ysA, hr, hw,
                                                   nullptr, b_ih1, b_hh1, ysB, t);
    }
    // layer 2
    hipMemsetAsync(hsa, 0, (size_t)BATCH * HP * 2, stream);
    for (int t = 0; t < T_STEPS; t++) {
        short* hr = (t & 1) ? hsb : hsa;
        short* hw = (t & 1) ? hsa : hsb;
        k_gru_step<true><<<grid, 384, 0, stream>>>(packW2, ysB, hr, hw,
                                                   nullptr, b_ih2, b_hh2, ysA, t);
    }
    // fc2 + transpose
    k_fc2<<<BATCH, 256, 0, stream>>>(ysA, packF, fc2_b, out);
}